// Round 2
// baseline (307.471 us; speedup 1.0000x reference)
//
#include <hip/hip_runtime.h>
#include <math.h>

#define BB 8
#define TT 4096
#define TP1 4097
#define HH 1024
#define NHD 16

__device__ __forceinline__ float dot4(const float4& a, const float4& b) {
  return a.x*b.x + a.y*b.y + a.z*b.z + a.w*b.w;
}

// ---------------- K1: qbuf[b][j] = 0.125*(cell[b,:]·Wq[j,:] + bq[j]) ----------------
__global__ __launch_bounds__(256) void k_q(const float* __restrict__ cell,
                                           const float* __restrict__ Wq,
                                           const float* __restrict__ bq,
                                           float* __restrict__ qbuf) {
  __shared__ float cs[BB * HH];  // 32 KB
  int tid = threadIdx.x;
  #pragma unroll
  for (int m = 0; m < 8; m++) {
    int idx4 = tid + (m << 8);
    ((float4*)cs)[idx4] = ((const float4*)cell)[idx4];
  }
  __syncthreads();
  int jj = tid >> 6, lane = tid & 63;
  int j = blockIdx.x * 4 + jj;
  float acc[BB];
  #pragma unroll
  for (int b = 0; b < BB; b++) acc[b] = 0.f;
  #pragma unroll
  for (int k = 0; k < 4; k++) {
    int i = (k << 8) + (lane << 2);
    float4 w = *(const float4*)&Wq[(size_t)j * HH + i];
    #pragma unroll
    for (int b = 0; b < BB; b++) acc[b] += dot4(w, *(const float4*)&cs[b * HH + i]);
  }
  #pragma unroll
  for (int b = 0; b < BB; b++) {
    acc[b] += __shfl_xor(acc[b], 1);  acc[b] += __shfl_xor(acc[b], 2);
    acc[b] += __shfl_xor(acc[b], 4);  acc[b] += __shfl_xor(acc[b], 8);
    acc[b] += __shfl_xor(acc[b], 16); acc[b] += __shfl_xor(acc[b], 32);
  }
  if (lane == 0) {
    float bqv = bq[j];
    #pragma unroll
    for (int b = 0; b < BB; b++) qbuf[b * HH + j] = 0.125f * (acc[b] + bqv);
  }
}

// ---------------- K2: qWkT[b][i][h] = sum_d qbuf[b][h*64+d]*Wk[h*64+d][i]; qbk[b][h] ----------------
__global__ __launch_bounds__(256) void k_qwk(const float* __restrict__ qbuf,
                                             const float* __restrict__ Wk,
                                             const float* __restrict__ bk,
                                             float* __restrict__ qWkT,
                                             float* __restrict__ qbk) {
  __shared__ float q_s[BB * 64];
  __shared__ float red[4 * 64 * 9];  // padded +1
  int tid = threadIdx.x;
  int h = blockIdx.x >> 4, ic = blockIdx.x & 15;
  if (tid < 128) {
    int b = tid >> 4, dq = tid & 15;
    ((float4*)q_s)[tid] = ((const float4*)qbuf)[(b << 8) + (h << 4) + dq];
  }
  __syncthreads();
  int dg = tid >> 6, lane = tid & 63;
  int i = (ic << 6) + lane;
  float acc[BB];
  #pragma unroll
  for (int b = 0; b < BB; b++) acc[b] = 0.f;
  #pragma unroll
  for (int dd = 0; dd < 16; dd++) {
    int d = (dg << 4) + dd;
    float wk = Wk[(size_t)((h << 6) + d) * HH + i];
    #pragma unroll
    for (int b = 0; b < BB; b++) acc[b] += q_s[(b << 6) + d] * wk;
  }
  #pragma unroll
  for (int b = 0; b < BB; b++) red[((dg << 6) + lane) * 9 + b] = acc[b];
  __syncthreads();
  #pragma unroll
  for (int r = 0; r < 2; r++) {
    int o = tid + (r << 8);           // 512 outputs = 64 i x 8 b
    int il = o >> 3, b = o & 7;
    float s = 0.f;
    #pragma unroll
    for (int g = 0; g < 4; g++) s += red[((g << 6) + il) * 9 + b];
    qWkT[((size_t)(b << 10) + (ic << 6) + il) * NHD + h] = s;
  }
  if (ic == 0 && tid < 8) {
    float s = 0.f;
    for (int d = 0; d < 64; d++) s += q_s[(tid << 6) + d] * bk[(h << 6) + d];
    qbk[tid * NHD + h] = s;
  }
}

// ---------------- K3 (FUSED): scores -> exp -> PV partial, single pass over hid ----------------
// grid 512 = b(8) x g(64). Block owns 64 rows (4 tiles of 16), 256 threads, 1 block/CU (134 KB LDS).
// LDS: qT[1024][16] (linear), kv[16][256 quads] XOR-swizzled (quad q of row r at q^r),
//      e[16][16], red[4][16][16], red2, qbk, msk.
// scores: thread (kq=tid>>4, rg=tid&15): row rg, i-slice kq*64..+63. qT read slot j^(kq&3)
//   -> conflict-free across kq; register block j holds h-quad j^(kq&3); resolved at shfl
//   reduce time with compile-time register permutation (partner register j^1 / j^2).
// PV: thread owns i-quad tid; acc4[16] persists across all 4 tiles; e read = pure broadcast.
// kv for tile n+1 is register-prefetched before PV of tile n (T14 issue-early/write-late).
#define QT_OFF   0
#define KV_OFF   16384
#define E_OFF    32768
#define RED_OFF  33024
#define RED2_OFF 34048
#define QBK_OFF  34112
#define MSK_OFF  34128

__global__ __launch_bounds__(256, 1) void k_sctx(const float* __restrict__ hid,
                                                 const float* __restrict__ qWkT,
                                                 const float* __restrict__ qbk,
                                                 const int* __restrict__ mask,
                                                 float* __restrict__ ctxp,
                                                 float* __restrict__ Spart) {
  __shared__ float S[34192];   // 133.6 KB
  int tid = threadIdx.x;
  int b = blockIdx.x >> 6, g = blockIdx.x & 63;
  int t0 = g << 6;
  int kq = tid >> 4, rg4 = tid & 15;
  int kqm = kq & 3;

  // ---- prologue: stage qT (linear), qbk, mask; kv tile 0 -> regs ----
  #pragma unroll
  for (int m = 0; m < 16; m++) {
    int idx = tid + (m << 8);       // 0..4095 float4s of qWkT[b]
    float4 v = ((const float4*)qWkT)[((size_t)b << 12) + idx];
    *(float4*)&S[QT_OFF + (idx << 2)] = v;
  }
  if (tid < NHD) S[QBK_OFF + tid] = qbk[b * NHD + tid];
  if (tid < 64) S[MSK_OFF + tid] = (float)mask[b * TT + t0 + tid];

  const float* src = hid + ((size_t)b * TP1 + t0) * HH;
  float4 stg[16];
  #pragma unroll
  for (int m = 0; m < 16; m++)
    stg[m] = *(const float4*)&src[(size_t)m * HH + (tid << 2)];

  float4 acc4[16];
  #pragma unroll
  for (int h = 0; h < 16; h++) acc4[h] = make_float4(0.f, 0.f, 0.f, 0.f);
  float sp = 0.f;

  #pragma unroll 1
  for (int tt = 0; tt < 4; tt++) {
    // ---- kv regs -> LDS (swizzled: quad q of row m at q^m) ----
    #pragma unroll
    for (int m = 0; m < 16; m++)
      *(float4*)&S[KV_OFF + (((m << 8) + (tid ^ m)) << 2)] = stg[m];
    __syncthreads();

    // ---- scores: row rg4, i-slice of 64 ----
    float accs[16];
    #pragma unroll
    for (int k = 0; k < 16; k++) accs[k] = 0.f;
    #pragma unroll
    for (int qq = 0; qq < 16; qq++) {
      int q = (kq << 4) + qq;
      float4 kvq = *(const float4*)&S[KV_OFF + (((rg4 << 8) + (q ^ rg4)) << 2)];
      #pragma unroll
      for (int c = 0; c < 4; c++) {
        float kvv = (&kvq.x)[c];
        int i16 = ((q << 2) + c) << 4;
        #pragma unroll
        for (int j = 0; j < 4; j++) {
          int s = j ^ kqm;   // conflict-free slot; content = h-quad s
          float4 qv = *(const float4*)&S[QT_OFF + i16 + (s << 2)];
          accs[(j << 2) + 0] += kvv * qv.x;
          accs[(j << 2) + 1] += kvv * qv.y;
          accs[(j << 2) + 2] += kvv * qv.z;
          accs[(j << 2) + 3] += kvv * qv.w;
        }
      }
    }
    // ---- reduce over 16 kq: register-permuted shfl (partner reg j^1, j^2), then LDS ----
    {
      float tmp[16];
      #pragma unroll
      for (int j = 0; j < 4; j++)
        #pragma unroll
        for (int c = 0; c < 4; c++)
          tmp[(j << 2) + c] = __shfl_xor(accs[((j ^ 1) << 2) + c], 16);
      #pragma unroll
      for (int k = 0; k < 16; k++) accs[k] += tmp[k];
      #pragma unroll
      for (int j = 0; j < 4; j++)
        #pragma unroll
        for (int c = 0; c < 4; c++)
          tmp[(j << 2) + c] = __shfl_xor(accs[((j ^ 2) << 2) + c], 32);
      #pragma unroll
      for (int k = 0; k < 16; k++) accs[k] += tmp[k];
    }
    if ((tid & 48) == 0) {   // kq&3==0 lanes: registers are h-ordered
      int w = tid >> 6;
      #pragma unroll
      for (int j = 0; j < 4; j++)
        *(float4*)&S[RED_OFF + (w << 8) + (rg4 << 4) + (j << 2)] =
            make_float4(accs[(j << 2)], accs[(j << 2) + 1],
                        accs[(j << 2) + 2], accs[(j << 2) + 3]);
    }
    __syncthreads();

    // ---- e = mask ? exp(score + qbk) : 0 ----
    {
      int rge = tid >> 4, he = tid & 15;
      float sv = S[RED_OFF + (rge << 4) + he] + S[RED_OFF + 256 + (rge << 4) + he] +
                 S[RED_OFF + 512 + (rge << 4) + he] + S[RED_OFF + 768 + (rge << 4) + he];
      sv += S[QBK_OFF + he];
      float mkf = S[MSK_OFF + (tt << 4) + rge];
      float ev = (mkf != 0.f) ? __expf(sv) : 0.f;
      S[E_OFF + (rge << 4) + he] = ev;
      sp += ev;
    }
    __syncthreads();

    // ---- prefetch next kv tile into regs (hides under PV) ----
    if (tt < 3) {
      const float* s2 = src + ((size_t)((tt + 1) << 4)) * HH;
      #pragma unroll
      for (int m = 0; m < 16; m++)
        stg[m] = *(const float4*)&s2[(size_t)m * HH + (tid << 2)];
    }

    // ---- PV: thread owns i-quad tid; e reads are pure broadcast ----
    #pragma unroll
    for (int r = 0; r < 16; r++) {
      float4 kvq = *(const float4*)&S[KV_OFF + (((r << 8) + (tid ^ r)) << 2)];
      float4 e0 = *(const float4*)&S[E_OFF + (r << 4)];
      float4 e1 = *(const float4*)&S[E_OFF + (r << 4) + 4];
      float4 e2 = *(const float4*)&S[E_OFF + (r << 4) + 8];
      float4 e3 = *(const float4*)&S[E_OFF + (r << 4) + 12];
      #define PVH(hh, ev) \
        acc4[hh].x += kvq.x * (ev); acc4[hh].y += kvq.y * (ev); \
        acc4[hh].z += kvq.z * (ev); acc4[hh].w += kvq.w * (ev);
      PVH(0, e0.x)  PVH(1, e0.y)  PVH(2, e0.z)  PVH(3, e0.w)
      PVH(4, e1.x)  PVH(5, e1.y)  PVH(6, e1.z)  PVH(7, e1.w)
      PVH(8, e2.x)  PVH(9, e2.y)  PVH(10, e2.z) PVH(11, e2.w)
      PVH(12, e3.x) PVH(13, e3.y) PVH(14, e3.z) PVH(15, e3.w)
      #undef PVH
    }
    __syncthreads();
  }

  // ---- write ctx partial: ctxp[b][g][h][i] ----
  {
    float* cp = ctxp + ((((size_t)b * 64 + g) * 16) << 10) + (tid << 2);
    #pragma unroll
    for (int h = 0; h < 16; h++)
      *(float4*)&cp[(size_t)h << 10] = acc4[h];
  }

  // ---- Spart[b][g][h] = sum over this block's 64 rows of e ----
  {
    sp += __shfl_xor(sp, 16);
    sp += __shfl_xor(sp, 32);
    int w = tid >> 6;
    if ((tid & 48) == 0) S[RED2_OFF + (w << 4) + (tid & 15)] = sp;
  }
  __syncthreads();
  if (tid < 16) {
    float s = S[RED2_OFF + tid] + S[RED2_OFF + 16 + tid] +
              S[RED2_OFF + 32 + tid] + S[RED2_OFF + 48 + tid];
    Spart[(((size_t)b << 6) + g) * NHD + tid] = s;
  }
}

// ---------------- K4: Sinv[b][h] = 1 / sum_g Spart[b][g][h] ----------------
__global__ void k_sinv(const float* __restrict__ Spart, float* __restrict__ Sinv) {
  int tid = threadIdx.x;  // 128
  int b = tid >> 4, h = tid & 15;
  float s = 0.f;
  #pragma unroll 8
  for (int c = 0; c < 64; c++) s += Spart[(size_t)((b << 6) + c) * NHD + h];
  Sinv[tid] = 1.f / s;
}

// ---------------- K4b: ctxin[b][h][i] = sum_g ctxp[b][g][h][i] ----------------
// grid 128 = b(8) x h(16); 256 threads; coalesced f4 loads, 64-deep.
__global__ __launch_bounds__(256) void k_reduce(const float* __restrict__ ctxp,
                                                float* __restrict__ ctxin) {
  int tid = threadIdx.x;
  int b = blockIdx.x >> 4, h = blockIdx.x & 15;
  const float4* cp4 = (const float4*)ctxp;
  float4 s = make_float4(0.f, 0.f, 0.f, 0.f);
  #pragma unroll 8
  for (int g = 0; g < 64; g++) {
    float4 v = cp4[((((size_t)b * 64 + g) * 16 + h) << 8) + tid];
    s.x += v.x; s.y += v.y; s.z += v.z; s.w += v.w;
  }
  ((float4*)ctxin)[(((size_t)(b << 4) + h) << 8) + tid] = s;
}

// ---------------- K6: out[b][h*64+(j%64)] = Sinv[b][h]*(Wv[j,:]·ctxin[b][h][:]) + bv[j] ----------------
__global__ __launch_bounds__(256) void k_out(const float* __restrict__ Wv,
                                             const float* __restrict__ bv,
                                             const float* __restrict__ ctxin,
                                             const float* __restrict__ Sinv,
                                             float* __restrict__ out) {
  __shared__ float cs[BB * HH];  // 32 KB
  int tid = threadIdx.x;
  int h = blockIdx.x >> 4;
  int j0 = blockIdx.x * 4;
  #pragma unroll
  for (int m = 0; m < 8; m++) {
    int idx4 = tid + (m << 8);
    int b = idx4 >> 8, i4 = idx4 & 255;
    ((float4*)cs)[idx4] = ((const float4*)ctxin)[(((b << 4) + h) << 8) + i4];
  }
  __syncthreads();
  int jj = tid >> 6, lane = tid & 63;
  int j = j0 + jj;
  float acc[BB];
  #pragma unroll
  for (int b = 0; b < BB; b++) acc[b] = 0.f;
  #pragma unroll
  for (int k = 0; k < 4; k++) {
    int i = (k << 8) + (lane << 2);
    float4 w = *(const float4*)&Wv[(size_t)j * HH + i];
    #pragma unroll
    for (int b = 0; b < BB; b++) acc[b] += dot4(w, *(const float4*)&cs[b * HH + i]);
  }
  #pragma unroll
  for (int b = 0; b < BB; b++) {
    acc[b] += __shfl_xor(acc[b], 1);  acc[b] += __shfl_xor(acc[b], 2);
    acc[b] += __shfl_xor(acc[b], 4);  acc[b] += __shfl_xor(acc[b], 8);
    acc[b] += __shfl_xor(acc[b], 16); acc[b] += __shfl_xor(acc[b], 32);
  }
  if (lane == 0) {
    float bvj = bv[j];
    #pragma unroll
    for (int b = 0; b < BB; b++)
      out[b * HH + j] = Sinv[b * NHD + h] * acc[b] + bvj;
  }
}

extern "C" void kernel_launch(void* const* d_in, const int* in_sizes, int n_in,
                              void* d_out, int out_size, void* d_ws, size_t ws_size,
                              hipStream_t stream) {
  const float* hid  = (const float*)d_in[0];  // (8, 4097, 1024)
  const float* cell = (const float*)d_in[1];  // (8, 1024)
  const float* Wq   = (const float*)d_in[2];
  const float* bq   = (const float*)d_in[3];
  const float* Wk   = (const float*)d_in[4];
  const float* bk   = (const float*)d_in[5];
  const float* Wv   = (const float*)d_in[6];
  const float* bv   = (const float*)d_in[7];
  const int*  mask  = (const int*)d_in[8];    // (8, 4096)
  float* out = (float*)d_out;                 // (8, 1024)

  float* ws = (float*)d_ws;
  float* qbuf    = ws;             // 8192
  float* qWkT    = ws + 8192;      // 131072   [b][i][16]
  float* qbk     = ws + 139264;    // 128
  float* Spart   = ws + 139392;    // 8192     [b][g(64)][16]
  float* Sinv    = ws + 147584;    // 128
  float* ctxin   = ws + 147712;    // 131072   [b][h][1024]
  float* ctxp    = ws + 278784;    // 8388608  [b][g(64)][h][1024] partials

  hipLaunchKernelGGL(k_q,      dim3(256), dim3(256), 0, stream, cell, Wq, bq, qbuf);
  hipLaunchKernelGGL(k_qwk,    dim3(256), dim3(256), 0, stream, qbuf, Wk, bk, qWkT, qbk);
  hipLaunchKernelGGL(k_sctx,   dim3(512), dim3(256), 0, stream, hid, qWkT, qbk, mask, ctxp, Spart);
  hipLaunchKernelGGL(k_sinv,   dim3(1),   dim3(128), 0, stream, Spart, Sinv);
  hipLaunchKernelGGL(k_reduce, dim3(128), dim3(256), 0, stream, ctxp, ctxin);
  hipLaunchKernelGGL(k_out,    dim3(256), dim3(256), 0, stream, Wv, bv, ctxin, Sinv, out);
}